// Round 13
// baseline (8222.464 us; speedup 1.0000x reference)
//
#include <hip/hip_runtime.h>
#include <hip/hip_bf16.h>
#include <hip/hip_fp16.h>

// 2-layer LSTM, B=32 T=512 F=1024. MFMA f16, layer-pipelined persistent kernel.
// R13 = R12 (decoupled barriers, depth-8 rings, lag-3, in-asm polls, fast gates)
// + CACHED h broadcast: producers write h sc0sc1 (LLC fresh); consumers, after
// mailbox-ready, issue buffer_inv sc1 (drop stale clean L2 lines) then read h
// with PLAIN CACHED loads -> 16 WGs/XCD share one L2 copy. Uncached LLC traffic
// drops ~16x (24 -> ~1.5 MB/round).

typedef _Float16 f16x8 __attribute__((ext_vector_type(8)));
typedef __fp16 fp16x2 __attribute__((ext_vector_type(2)));
typedef float f32x4 __attribute__((ext_vector_type(4)));

#define NB 32
#define NTT 512
#define NF 1024
#define NG 4096
#define TFE (NTT * NF)
#define NWG 256
#define NTHR 512

#define W_F16X8 8192                    // [64 s][2 ntile][64 lane] f16x8
#define W_BYTES (W_F16X8 * 16)          // 131072
#define ZQSEG 33
#define Z_FLOATS (8 * 16 * ZQSEG)
#define LDS_BYTES (W_BYTES + Z_FLOATS * 4)   // 147968
#define RINGB 65536                     // one h slot: 32 b x 1024 f16
#define DEPTH 8
#define MBOX 4096                       // u32 index of mailbox region (16KB in)

#define LOG2E 1.44269504f

__device__ __forceinline__ float sigm(float v) {
  return __builtin_amdgcn_rcpf(1.0f + __builtin_amdgcn_exp2f(-LOG2E * v));
}
__device__ __forceinline__ float tanh_s(float v) {
  return 2.0f * __builtin_amdgcn_rcpf(1.0f + __builtin_amdgcn_exp2f(-2.0f * LOG2E * v)) - 1.0f;
}

__device__ __forceinline__ unsigned pk(float a, float b) {
  union { fp16x2 h2; unsigned u; } c;
  c.h2 = __builtin_amdgcn_cvt_pkrtz(a, b);
  return c.u;
}

__device__ __forceinline__ f16x8 cvt8(f32x4 lo, f32x4 hi) {
  union { unsigned u[4]; f16x8 h8; } u;
  u.u[0] = pk(lo[0], lo[1]);
  u.u[1] = pk(lo[2], lo[3]);
  u.u[2] = pk(hi[0], hi[1]);
  u.u[3] = pk(hi[2], hi[3]);
  return u.h8;
}

// 4 CACHED 16B loads from p + {0,64,128,192} (L2-cacheable h broadcast reads)
__device__ __forceinline__ void ld4c(f16x8 o[4], const char* p) {
  asm volatile("global_load_dwordx4 %0, %4, off\n\t"
               "global_load_dwordx4 %1, %4, off offset:64\n\t"
               "global_load_dwordx4 %2, %4, off offset:128\n\t"
               "global_load_dwordx4 %3, %4, off offset:192"
               : "=&v"(o[0]), "=&v"(o[1]), "=&v"(o[2]), "=&v"(o[3])
               : "v"(p) : "memory");
}

__global__ __launch_bounds__(NTHR, 1) void lstm_persist(
    const float* __restrict__ x,
    const float* __restrict__ Wi0, const float* __restrict__ Wh0, const float* __restrict__ bv0,
    const float* __restrict__ Wi1, const float* __restrict__ Wh1, const float* __restrict__ bv1,
    float* __restrict__ out, unsigned short* __restrict__ hring_u16,
    unsigned* __restrict__ bar) {
  extern __shared__ char lds[];
  f16x8* Wl = (f16x8*)lds;                 // Wl[(s*2+ntile)*64 + lane]
  float* Zr = (float*)(lds + W_BYTES);     // Zr[(w*16+row)*33 + col]

  const int wg = blockIdx.x;
  const int tid = threadIdx.x;
  const int role = wg >> 7;        // 0: layer 0, 1: layer 1
  const int fg = wg & 127;
  const int fbase = fg * 8;
  const int w = tid >> 6;          // wave 0..7
  const int Kq = w >> 1;
  const int mt = w & 1;
  const int lane = tid & 63;
  const int lr = lane & 15;
  const int g = lane >> 4;
  const bool master = (fg == 0);   // wg 0 masters A, wg 128 masters B
  unsigned gen = 0;

  auto arrive = [&]() {
    asm volatile("s_waitcnt vmcnt(0) lgkmcnt(0)" ::: "memory");
    __syncthreads();
    ++gen;
    if (tid == 0)
      asm volatile("global_store_dword %0, %1, off sc0 sc1"
                   :: "v"(&bar[wg * 16]), "v"(gen) : "memory");
    if (master) {
      if (tid < 64) {
        const unsigned* fa = &bar[(role * 128 + 2 * tid) * 16];
        const unsigned* fb = &bar[(role * 128 + 2 * tid + 1) * 16];
        asm volatile("L%=:\n\t"
                     "global_load_dword v20, %0, off sc0 sc1\n\t"
                     "global_load_dword v21, %1, off sc0 sc1\n\t"
                     "s_waitcnt vmcnt(0)\n\t"
                     "v_cmp_lt_u32 vcc, v20, %2\n\t"
                     "s_mov_b64 s[14:15], vcc\n\t"
                     "v_cmp_lt_u32 vcc, v21, %2\n\t"
                     "s_or_b64 vcc, vcc, s[14:15]\n\t"
                     "s_cbranch_vccnz L%="
                     :: "v"(fa), "v"(fb), "v"(gen)
                     : "memory", "v20", "v21", "vcc", "s14", "s15");
      }
      __syncthreads();
      if (tid < 256)
        asm volatile("global_store_dword %0, %1, off sc0 sc1"
                     :: "v"(&bar[MBOX + tid * 16 + role]), "v"(gen) : "memory");
    }
  };

  // wait until mailbox A>=minA and B>=minB, then drop stale L2 lines so the
  // following CACHED h loads see fresh LLC data (inv preserves dirty lines).
  auto waitAB = [&](unsigned minA, unsigned minB) {
    const unsigned* mb = &bar[MBOX + wg * 16];
    asm volatile("L%=:\n\t"
                 "global_load_dwordx2 v[20:21], %0, off sc0 sc1\n\t"
                 "s_waitcnt vmcnt(0)\n\t"
                 "v_cmp_lt_u32 vcc, v20, %1\n\t"
                 "s_mov_b64 s[14:15], vcc\n\t"
                 "v_cmp_lt_u32 vcc, v21, %2\n\t"
                 "s_or_b64 vcc, vcc, s[14:15]\n\t"
                 "s_cbranch_vccnz L%=\n\t"
                 "buffer_inv sc1\n\t"
                 "s_waitcnt vmcnt(0)"
                 :: "v"(mb), "v"(minA), "v"(minB)
                 : "memory", "v20", "v21", "vcc", "s14", "s15");
  };

  const float* Wi = role ? Wi1 : Wi0;
  const float* Wh = role ? Wh1 : Wh0;
  const float* bv = role ? bv1 : bv0;
  char* h0b = (char*)hring_u16;                        // h0 ring: DEPTH slots
  char* h1b = (char*)hring_u16 + DEPTH * RINGB;        // h1 ring
  unsigned* hmine = (unsigned*)(role ? h1b : h0b);

  // ---- one-time W slice -> f16 LDS in B-fragment order ----
  for (int idx = tid; idx < 16384; idx += NTHR) {
    const int k = idx >> 3, chunk = idx & 7;
    const int q = chunk >> 1, half = chunk & 1;
    const float* src = (k < NF) ? (Wi + (size_t)k * NG) : (Wh + (size_t)(k - NF) * NG);
    const f32x4 v = *(const f32x4*)(src + q * NF + fbase + half * 4);
    const int s = k >> 5, kg = (k >> 3) & 3, jj = k & 7;
#pragma unroll
    for (int j = 0; j < 4; ++j) {
      const int c = q * 8 + half * 4 + j;
      _Float16* dst = (_Float16*)&Wl[((s * 2 + (c >> 4)) * 64) + kg * 16 + (c & 15)];
      dst[jj] = (_Float16)v[j];
    }
  }
  if (tid < 128) {
    const int b = tid >> 2, fp = tid & 3;
    __hip_atomic_store(&hmine[b * 512 + (fbase >> 1) + fp], 0u,
                       __ATOMIC_RELAXED, __HIP_MEMORY_SCOPE_AGENT);
  }
  float bias[4][2];
  if (tid < 128) {
    const int fp = tid & 3;
#pragma unroll
    for (int q = 0; q < 4; ++q) {
      bias[q][0] = bv[q * NF + fbase + 2 * fp];
      bias[q][1] = bv[q * NF + fbase + 2 * fp + 1];
    }
  }
  float cst[2] = {0.f, 0.f};
  __syncthreads();
  arrive();         // gen 1: W staged + ring slot 0 zeroed
  waitAB(1, 1);

  const int nrounds = role ? (NTT + 3) : NTT;   // L1 lag 3
  for (int rd = 0; rd < nrounds; ++rd) {
    const bool doit = role == 0 ? true : (rd >= 3);
    const int t = role == 0 ? rd : rd - 3;

    if (doit) {
      f32x4 acc0 = {0.f, 0.f, 0.f, 0.f}, acc1 = {0.f, 0.f, 0.f, 0.f};
      const int brow = mt * 16 + lr;

      if (role == 0 && w < 4) {
        const float* xp = x + (size_t)brow * TFE + (size_t)t * NF + Kq * 512 + g * 8;
#pragma unroll
        for (int ks = 0; ks < 16; ++ks) {
          const int s = Kq * 16 + ks;
          const f32x4 al = *(const f32x4*)(xp + ks * 32);
          const f32x4 ah = *(const f32x4*)(xp + ks * 32 + 4);
          const f16x8 A = cvt8(al, ah);
          acc0 = __builtin_amdgcn_mfma_f32_16x16x32_f16(A, Wl[(s * 2 + 0) * 64 + lane], acc0, 0, 0, 0);
          acc1 = __builtin_amdgcn_mfma_f32_16x16x32_f16(A, Wl[(s * 2 + 1) * 64 + lane], acc1, 0, 0, 0);
        }
      } else {
        unsigned minA = 0, minB = 0;
        const char* hp;
        if (role == 0) {
          minA = rd + 1;
          minB = (rd >= 4) ? (unsigned)(rd - 3) : 0u;
          hp = h0b + (size_t)(rd & 7) * RINGB + brow * 2048
               + ((Kq - 2) * 512 + g * 8) * 2;
        } else if (Kq < 2) {
          minA = rd - 1;
          hp = h0b + (size_t)((rd - 2) & 7) * RINGB + brow * 2048
               + (Kq * 512 + g * 8) * 2;            // y0(t)=h0(rd-2)
        } else {
          minB = (rd == 3) ? 1u : (unsigned)(rd + 1);
          hp = h1b + (size_t)((rd - 3) & 7) * RINGB + brow * 2048
               + ((Kq - 2) * 512 + g * 8) * 2;      // h1(t-1)
        }
        waitAB(minA, minB);   // includes buffer_inv sc1 on success

        f16x8 T[16];
        ld4c(T + 0, hp);       ld4c(T + 4, hp + 256);
        ld4c(T + 8, hp + 512); ld4c(T + 12, hp + 768);
        asm volatile("s_waitcnt vmcnt(12)" ::: "memory");
        __builtin_amdgcn_sched_barrier(0);
#pragma unroll
        for (int kk = 0; kk < 4; ++kk) {
          const int s = Kq * 16 + kk;
          acc0 = __builtin_amdgcn_mfma_f32_16x16x32_f16(T[kk], Wl[(s * 2 + 0) * 64 + lane], acc0, 0, 0, 0);
          acc1 = __builtin_amdgcn_mfma_f32_16x16x32_f16(T[kk], Wl[(s * 2 + 1) * 64 + lane], acc1, 0, 0, 0);
        }
        asm volatile("s_waitcnt vmcnt(8)" ::: "memory");
        __builtin_amdgcn_sched_barrier(0);
#pragma unroll
        for (int kk = 0; kk < 4; ++kk) {
          const int s = Kq * 16 + 4 + kk;
          acc0 = __builtin_amdgcn_mfma_f32_16x16x32_f16(T[4 + kk], Wl[(s * 2 + 0) * 64 + lane], acc0, 0, 0, 0);
          acc1 = __builtin_amdgcn_mfma_f32_16x16x32_f16(T[4 + kk], Wl[(s * 2 + 1) * 64 + lane], acc1, 0, 0, 0);
        }
        asm volatile("s_waitcnt vmcnt(4)" ::: "memory");
        __builtin_amdgcn_sched_barrier(0);
#pragma unroll
        for (int kk = 0; kk < 4; ++kk) {
          const int s = Kq * 16 + 8 + kk;
          acc0 = __builtin_amdgcn_mfma_f32_16x16x32_f16(T[8 + kk], Wl[(s * 2 + 0) * 64 + lane], acc0, 0, 0, 0);
          acc1 = __builtin_amdgcn_mfma_f32_16x16x32_f16(T[8 + kk], Wl[(s * 2 + 1) * 64 + lane], acc1, 0, 0, 0);
        }
        asm volatile("s_waitcnt vmcnt(0)" ::: "memory");
        __builtin_amdgcn_sched_barrier(0);
#pragma unroll
        for (int kk = 0; kk < 4; ++kk) {
          const int s = Kq * 16 + 12 + kk;
          acc0 = __builtin_amdgcn_mfma_f32_16x16x32_f16(T[12 + kk], Wl[(s * 2 + 0) * 64 + lane], acc0, 0, 0, 0);
          acc1 = __builtin_amdgcn_mfma_f32_16x16x32_f16(T[12 + kk], Wl[(s * 2 + 1) * 64 + lane], acc1, 0, 0, 0);
        }
      }

      {
        float* zb = Zr + (size_t)w * 16 * ZQSEG;
#pragma unroll
        for (int reg = 0; reg < 4; ++reg) {
          zb[(g * 4 + reg) * ZQSEG + lr] = acc0[reg];
          zb[(g * 4 + reg) * ZQSEG + 16 + lr] = acc1[reg];
        }
      }
    }
    __syncthreads();

    if (doit && tid < 128) {
      const int b = tid >> 2, fp = tid & 3;
      const int bmt = b >> 4, row = b & 15;
      float hv[2];
#pragma unroll
      for (int e = 0; e < 2; ++e) {
        const int f = 2 * fp + e;
        float zq[4];
#pragma unroll
        for (int q = 0; q < 4; ++q) {
          const int c = q * 8 + f;
          float sum = bias[q][e];
#pragma unroll
          for (int kq = 0; kq < 4; ++kq)
            sum += Zr[((kq * 2 + bmt) * 16 + row) * ZQSEG + c];
          zq[q] = sum;
        }
        const float cn = sigm(zq[1]) * cst[e] + sigm(zq[0]) * tanh_s(zq[2]);
        hv[e] = sigm(zq[3]) * tanh_s(cn);
        cst[e] = cn;
      }
      const int wslot = (t + 1) & 7;
      __hip_atomic_store(&hmine[(size_t)wslot * (RINGB / 4) + b * 512 + (fbase >> 1) + fp],
                         pk(hv[0], hv[1]), __ATOMIC_RELAXED, __HIP_MEMORY_SCOPE_AGENT);
      if (role == 1)
        *(float2*)(out + (size_t)b * TFE + (size_t)t * NF + fbase + 2 * fp) =
            make_float2(hv[0], hv[1]);
    }
    arrive();
  }
}

extern "C" void kernel_launch(void* const* d_in, const int* in_sizes, int n_in,
                              void* d_out, int out_size, void* d_ws, size_t ws_size,
                              hipStream_t stream) {
  (void)in_sizes; (void)n_in; (void)out_size; (void)ws_size;
  const float* x   = (const float*)d_in[0];
  const float* Wi0 = (const float*)d_in[1];
  const float* Wh0 = (const float*)d_in[2];
  const float* b0  = (const float*)d_in[3];
  const float* Wi1 = (const float*)d_in[4];
  const float* Wh1 = (const float*)d_in[5];
  const float* b1  = (const float*)d_in[6];
  float* out = (float*)d_out;

  unsigned short* hring = (unsigned short*)d_ws;       // h0[8]+h1[8] slots, 1MB
  unsigned* bar = (unsigned*)((char*)d_ws + 2 * DEPTH * RINGB);  // flags+mbox 32KB

  (void)hipMemsetAsync(bar, 0, 32768, stream);  // replay-safe barrier reset

  (void)hipFuncSetAttribute((const void*)lstm_persist,
                            hipFuncAttributeMaxDynamicSharedMemorySize, LDS_BYTES);

  lstm_persist<<<dim3(NWG), dim3(NTHR), LDS_BYTES, stream>>>(
      x, Wi0, Wh0, b0, Wi1, Wh1, b1, out, hring, bar);
}

// Round 14
// 8109.573 us; speedup vs baseline: 1.0139x; 1.0139x over previous
//
#include <hip/hip_runtime.h>
#include <hip/hip_bf16.h>
#include <hip/hip_fp16.h>

// 2-layer LSTM, B=32 T=512 F=1024. MFMA f16, WAVE-AUTONOMOUS persistent kernel.
// R14: 256 WGs x 128 thr (2 waves = M-tiles mt0/mt1, 1 WG/CU). Each wave owns a
// 16x32 z-tile over FULL K=2048 (64 chained MFMAs, 2 accs) -> no cross-wave
// reduce, no Zr LDS, NO in-loop syncthreads. Gates in-wave from accs via
// shfl_xor(8) (cols q*8+f sit in lanes f/f+8 of acc0/acc1); c-state in VGPRs;
// h stored as 2B f16 sc0sc1 write-through. Per-WAVE flags (256/layer);
// masters (WG0/WG128 wave0) poll + fan out; split-phase mbox wait (R10).
// L0: x-phase (cached fp32+cvt, s=0..31) BEFORE poll -> hides sync chain.
// L1: y0-phase (h0 ring, s=0..31) after pre-satisfied A-wait, then serial
// B-wait + h1-phase (s=32..63). Decoupled per-layer barriers, depth-8 rings,
// lag-3 (R11/R12). R13's buffer_inv cached-broadcast REVERTED (full-L2 inv
// per round serialized + killed x locality: 2.2x regression).

typedef _Float16 f16x8 __attribute__((ext_vector_type(8)));
typedef __fp16 fp16x2 __attribute__((ext_vector_type(2)));
typedef float f32x4 __attribute__((ext_vector_type(4)));

#define NB 32
#define NTT 512
#define NF 1024
#define NG 4096
#define TFE (NTT * NF)
#define NWG 256
#define NTHR 128

#define W_BYTES 131072                  // [64 s][2 nt][64 lane] f16x8
#define LDS_BYTES W_BYTES
#define RINGB 65536                     // one h slot: 32 b x 1024 f16
#define DEPTH 8
#define MBOX 8192                       // u32 idx; flags: 512 x 64B = 32KB
#define LOG2E 1.44269504f

__device__ __forceinline__ float sigm(float v) {
  return __builtin_amdgcn_rcpf(1.0f + __builtin_amdgcn_exp2f(-LOG2E * v));
}
__device__ __forceinline__ float tanh_s(float v) {
  return 2.0f * __builtin_amdgcn_rcpf(1.0f + __builtin_amdgcn_exp2f(-2.0f * LOG2E * v)) - 1.0f;
}

__device__ __forceinline__ unsigned pk(float a, float b) {
  union { fp16x2 h2; unsigned u; } c;
  c.h2 = __builtin_amdgcn_cvt_pkrtz(a, b);
  return c.u;
}

__device__ __forceinline__ f16x8 cvt8(f32x4 lo, f32x4 hi) {
  union { unsigned u[4]; f16x8 h8; } u;
  u.u[0] = pk(lo[0], lo[1]);
  u.u[1] = pk(lo[2], lo[3]);
  u.u[2] = pk(hi[0], hi[1]);
  u.u[3] = pk(hi[2], hi[3]);
  return u.h8;
}

// 4 coherent 16B loads (one lane's A-frags for 4 consecutive ks)
__device__ __forceinline__ void ld4(f16x8 o[4], const char* p) {
  asm volatile("global_load_dwordx4 %0, %4, off sc0 sc1\n\t"
               "global_load_dwordx4 %1, %4, off offset:64 sc0 sc1\n\t"
               "global_load_dwordx4 %2, %4, off offset:128 sc0 sc1\n\t"
               "global_load_dwordx4 %3, %4, off offset:192 sc0 sc1"
               : "=&v"(o[0]), "=&v"(o[1]), "=&v"(o[2]), "=&v"(o[3])
               : "v"(p) : "memory");
}

__global__ __launch_bounds__(NTHR, 1) void lstm_persist(
    const float* __restrict__ x,
    const float* __restrict__ Wi0, const float* __restrict__ Wh0, const float* __restrict__ bv0,
    const float* __restrict__ Wi1, const float* __restrict__ Wh1, const float* __restrict__ bv1,
    float* __restrict__ out, unsigned short* __restrict__ hring_u16,
    unsigned* __restrict__ bar) {
  extern __shared__ char lds[];
  f16x8* Wl = (f16x8*)lds;                 // Wl[(s*2+nt)*64 + lane]

  const int wg = blockIdx.x;
  const int tid = threadIdx.x;
  const int role = wg >> 7;        // 0: layer 0, 1: layer 1
  const int fg = wg & 127;
  const int fbase = fg * 8;
  const int mt = tid >> 6;         // wave = M-tile (16 batches)
  const int lane = tid & 63;
  const int n = lane & 15;         // fragment row / C-col index
  const int g = lane >> 4;         // k-group / C-row group
  unsigned gen = 0;

  // per-wave arrival; masters (fg==0, wave0) detect 256 flags + fan out.
  auto arrive = [&]() {
    asm volatile("s_waitcnt vmcnt(0) lgkmcnt(0)" ::: "memory");
    ++gen;
    if (lane == 0)
      asm volatile("global_store_dword %0, %1, off sc0 sc1"
                   :: "v"(&bar[(wg * 2 + mt) * 16]), "v"(gen) : "memory");
    if (fg == 0 && mt == 0) {
      const unsigned* f0 = &bar[(role * 256 + lane * 4 + 0) * 16];
      const unsigned* f1 = &bar[(role * 256 + lane * 4 + 1) * 16];
      const unsigned* f2 = &bar[(role * 256 + lane * 4 + 2) * 16];
      const unsigned* f3 = &bar[(role * 256 + lane * 4 + 3) * 16];
      asm volatile("L%=:\n\t"
                   "global_load_dword v20, %0, off sc0 sc1\n\t"
                   "global_load_dword v21, %1, off sc0 sc1\n\t"
                   "global_load_dword v22, %2, off sc0 sc1\n\t"
                   "global_load_dword v23, %3, off sc0 sc1\n\t"
                   "s_waitcnt vmcnt(0)\n\t"
                   "v_cmp_lt_u32 vcc, v20, %4\n\t"
                   "s_mov_b64 s[14:15], vcc\n\t"
                   "v_cmp_lt_u32 vcc, v21, %4\n\t"
                   "s_or_b64 s[14:15], vcc, s[14:15]\n\t"
                   "v_cmp_lt_u32 vcc, v22, %4\n\t"
                   "s_or_b64 s[14:15], vcc, s[14:15]\n\t"
                   "v_cmp_lt_u32 vcc, v23, %4\n\t"
                   "s_or_b64 vcc, vcc, s[14:15]\n\t"
                   "s_cbranch_vccnz L%="
                   :: "v"(f0), "v"(f1), "v"(f2), "v"(f3), "v"(gen)
                   : "memory", "v20", "v21", "v22", "v23", "vcc", "s14", "s15");
#pragma unroll
      for (int j = 0; j < 4; ++j)
        asm volatile("global_store_dword %0, %1, off sc0 sc1"
                     :: "v"(&bar[MBOX + (lane * 4 + j) * 16 + role]), "v"(gen) : "memory");
    }
  };

  // wait until my mbox [A,B] >= [minA,minB] (all lanes same line, in-asm loop)
  auto waitAB = [&](unsigned minA, unsigned minB) {
    const unsigned* mb = &bar[MBOX + wg * 16];
    asm volatile("L%=:\n\t"
                 "global_load_dwordx2 v[20:21], %0, off sc0 sc1\n\t"
                 "s_waitcnt vmcnt(0)\n\t"
                 "v_cmp_lt_u32 vcc, v20, %1\n\t"
                 "s_mov_b64 s[14:15], vcc\n\t"
                 "v_cmp_lt_u32 vcc, v21, %2\n\t"
                 "s_or_b64 vcc, vcc, s[14:15]\n\t"
                 "s_cbranch_vccnz L%="
                 :: "v"(mb), "v"(minA), "v"(minB)
                 : "memory", "v20", "v21", "vcc", "s14", "s15");
  };

  const float* Wi = role ? Wi1 : Wi0;
  const float* Wh = role ? Wh1 : Wh0;
  const float* bv = role ? bv1 : bv0;
  char* h0b = (char*)hring_u16;                        // h0 ring: DEPTH slots
  char* h1b = (char*)hring_u16 + DEPTH * RINGB;        // h1 ring
  char* hmine = role ? h1b : h0b;

  // ---- one-time W slice -> f16 LDS in B-fragment order ----
  for (int idx = tid; idx < 16384; idx += NTHR) {
    const int k = idx >> 3, chunk = idx & 7;
    const int q = chunk >> 1, half = chunk & 1;
    const float* src = (k < NF) ? (Wi + (size_t)k * NG) : (Wh + (size_t)(k - NF) * NG);
    const f32x4 v = *(const f32x4*)(src + q * NF + fbase + half * 4);
    const int s = k >> 5, kg = (k >> 3) & 3, jj = k & 7;
#pragma unroll
    for (int j = 0; j < 4; ++j) {
      const int c = q * 8 + half * 4 + j;
      _Float16* dst = (_Float16*)&Wl[((s * 2 + (c >> 4)) * 64) + kg * 16 + (c & 15)];
      dst[jj] = (_Float16)v[j];
    }
  }
  // zero own ring slot 0 (all 128 threads: b=tid>>2, dword fp=tid&3)
  {
    const int b = tid >> 2, fp = tid & 3;
    __hip_atomic_store((unsigned*)hmine + b * 512 + (fbase >> 1) + fp, 0u,
                       __ATOMIC_RELAXED, __HIP_MEMORY_SCOPE_AGENT);
  }
  float bq[4];
#pragma unroll
  for (int q = 0; q < 4; ++q) bq[q] = bv[q * NF + fbase + (lane & 7)];
  float cst[4] = {0.f, 0.f, 0.f, 0.f};
  __syncthreads();       // Wl fully staged before either wave reads it
  arrive();              // gen 1: W + ring slot 0 ready
  waitAB(1, 1);

  // full-K h/y0 MFMA phase: 32 frag loads up-front, 4 consume groups of 8 ks
  auto hphase = [&](const char* hp, int sbase, f32x4& a0, f32x4& a1) {
    f16x8 T[32];
#pragma unroll
    for (int q = 0; q < 8; ++q) ld4(T + q * 4, hp + q * 256);
    asm volatile("s_waitcnt vmcnt(24)" ::: "memory");
    __builtin_amdgcn_sched_barrier(0);
#pragma unroll
    for (int kk = 0; kk < 8; ++kk) {
      const int s = sbase + kk;
      a0 = __builtin_amdgcn_mfma_f32_16x16x32_f16(T[kk], Wl[(s * 2 + 0) * 64 + lane], a0, 0, 0, 0);
      a1 = __builtin_amdgcn_mfma_f32_16x16x32_f16(T[kk], Wl[(s * 2 + 1) * 64 + lane], a1, 0, 0, 0);
    }
    asm volatile("s_waitcnt vmcnt(16)" ::: "memory");
    __builtin_amdgcn_sched_barrier(0);
#pragma unroll
    for (int kk = 8; kk < 16; ++kk) {
      const int s = sbase + kk;
      a0 = __builtin_amdgcn_mfma_f32_16x16x32_f16(T[kk], Wl[(s * 2 + 0) * 64 + lane], a0, 0, 0, 0);
      a1 = __builtin_amdgcn_mfma_f32_16x16x32_f16(T[kk], Wl[(s * 2 + 1) * 64 + lane], a1, 0, 0, 0);
    }
    asm volatile("s_waitcnt vmcnt(8)" ::: "memory");
    __builtin_amdgcn_sched_barrier(0);
#pragma unroll
    for (int kk = 16; kk < 24; ++kk) {
      const int s = sbase + kk;
      a0 = __builtin_amdgcn_mfma_f32_16x16x32_f16(T[kk], Wl[(s * 2 + 0) * 64 + lane], a0, 0, 0, 0);
      a1 = __builtin_amdgcn_mfma_f32_16x16x32_f16(T[kk], Wl[(s * 2 + 1) * 64 + lane], a1, 0, 0, 0);
    }
    asm volatile("s_waitcnt vmcnt(0)" ::: "memory");
    __builtin_amdgcn_sched_barrier(0);
#pragma unroll
    for (int kk = 24; kk < 32; ++kk) {
      const int s = sbase + kk;
      a0 = __builtin_amdgcn_mfma_f32_16x16x32_f16(T[kk], Wl[(s * 2 + 0) * 64 + lane], a0, 0, 0, 0);
      a1 = __builtin_amdgcn_mfma_f32_16x16x32_f16(T[kk], Wl[(s * 2 + 1) * 64 + lane], a1, 0, 0, 0);
    }
  };

  const int nrounds = role ? (NTT + 3) : NTT;   // L1 lag 3
  for (int rd = 0; rd < nrounds; ++rd) {
    const bool doit = role == 0 ? true : (rd >= 3);
    const int t = role == 0 ? rd : rd - 3;

    if (doit) {
      f32x4 a0 = {0.f, 0.f, 0.f, 0.f}, a1 = {0.f, 0.f, 0.f, 0.f};
      const int brow = mt * 16 + n;

      if (role == 0) {
        // x-phase first: cached fp32 loads + cvt, hides the sync chain
        const float* xp = x + (size_t)brow * TFE + (size_t)t * NF + g * 8;
#pragma unroll 8
        for (int ks = 0; ks < 32; ++ks) {
          const f32x4 al = *(const f32x4*)(xp + ks * 32);
          const f32x4 ah = *(const f32x4*)(xp + ks * 32 + 4);
          const f16x8 A = cvt8(al, ah);
          a0 = __builtin_amdgcn_mfma_f32_16x16x32_f16(A, Wl[(ks * 2 + 0) * 64 + lane], a0, 0, 0, 0);
          a1 = __builtin_amdgcn_mfma_f32_16x16x32_f16(A, Wl[(ks * 2 + 1) * 64 + lane], a1, 0, 0, 0);
        }
        const unsigned minB = (rd >= 4) ? (unsigned)(rd - 3) : 0u;  // ring guard
        waitAB(rd + 1, minB);
        hphase(h0b + (size_t)(rd & 7) * RINGB + brow * 2048 + g * 16, 32, a0, a1);
      } else {
        waitAB(rd - 1, 0);   // y0 ready (pre-satisfied via lag slack)
        hphase(h0b + (size_t)((rd - 2) & 7) * RINGB + brow * 2048 + g * 16, 0, a0, a1);
        const unsigned minB = (rd == 3) ? 1u : (unsigned)(rd + 1);  // own recurrence
        waitAB(0, minB);
        hphase(h1b + (size_t)((rd - 3) & 7) * RINGB + brow * 2048 + g * 16, 32, a0, a1);
      }

      // ---- in-wave gates: cols q*8+f are in lanes f / f+8 of acc0/acc1 ----
      float o0[4], o1[4];
#pragma unroll
      for (int r = 0; r < 4; ++r) {
        o0[r] = __shfl_xor(a0[r], 8, 64);
        o1[r] = __shfl_xor(a1[r], 8, 64);
      }
      if (n < 8) {
        char* hdst = hmine + (size_t)((t + 1) & 7) * RINGB;
#pragma unroll
        for (int r = 0; r < 4; ++r) {
          const float zi = a0[r] + bq[0];
          const float zf = o0[r] + bq[1];
          const float zg = a1[r] + bq[2];
          const float zo = o1[r] + bq[3];
          const float cn = sigm(zf) * cst[r] + sigm(zi) * tanh_s(zg);
          const float hv = sigm(zo) * tanh_s(cn);
          cst[r] = cn;
          const int b = mt * 16 + g * 4 + r;
          const unsigned hu = pk(hv, hv);
          asm volatile("global_store_short %0, %1, off sc0 sc1"
                       :: "v"(hdst + b * 2048 + (fbase + n) * 2), "v"(hu) : "memory");
          if (role == 1)
            out[(size_t)b * TFE + (size_t)t * NF + fbase + n] = hv;
        }
      }
    }
    arrive();   // drain h/out stores, flag my wave; master pipelines detect+fanout
  }
}

extern "C" void kernel_launch(void* const* d_in, const int* in_sizes, int n_in,
                              void* d_out, int out_size, void* d_ws, size_t ws_size,
                              hipStream_t stream) {
  (void)in_sizes; (void)n_in; (void)out_size; (void)ws_size;
  const float* x   = (const float*)d_in[0];
  const float* Wi0 = (const float*)d_in[1];
  const float* Wh0 = (const float*)d_in[2];
  const float* b0  = (const float*)d_in[3];
  const float* Wi1 = (const float*)d_in[4];
  const float* Wh1 = (const float*)d_in[5];
  const float* b1  = (const float*)d_in[6];
  float* out = (float*)d_out;

  unsigned short* hring = (unsigned short*)d_ws;       // h0[8]+h1[8] slots, 1MB
  unsigned* bar = (unsigned*)((char*)d_ws + 2 * DEPTH * RINGB);  // flags 32KB + mbox 16KB

  (void)hipMemsetAsync(bar, 0, 49152, stream);  // replay-safe barrier reset

  (void)hipFuncSetAttribute((const void*)lstm_persist,
                            hipFuncAttributeMaxDynamicSharedMemorySize, LDS_BYTES);

  lstm_persist<<<dim3(NWG), dim3(NTHR), LDS_BYTES, stream>>>(
      x, Wi0, Wh0, b0, Wi1, Wh1, b1, out, hring, bar);
}

// Round 16
// 5163.231 us; speedup vs baseline: 1.5925x; 1.5706x over previous
//
#include <hip/hip_runtime.h>
#include <hip/hip_bf16.h>
#include <hip/hip_fp16.h>

// 2-layer LSTM, B=32 T=512 F=1024. MFMA f16, layer-pipelined persistent kernel.
// R16 = R15 (sentinel data-self-sync) with the R15 BUG FIXED: hphase's W-row
// base must be Kq*16 per wave (R15 hard-coded 32/0/32 at the call sites, so
// Kq=3/1/3 waves used the wrong W rows -> absmax 0.47).
// Structure: 256 WGs x 512 thr (8 waves: 4 K-quarters x 2 M-tiles), Zr reduce,
// gates on 128 thr. h rings are self-announcing: slots poisoned 0xFFFFFFFF
// (impossible f16x2 from tanh-bounded h); consumers poll the h lines (sc0sc1)
// until no sentinel. No flag hop / master / fanout / mailbox on critical path.
// L1 re-poisons consumed slots (gated by L1 flags); L0 x-waves throttle on L1
// flags for ring-overwrite protection. Depth-8 rings, lag-3.

typedef _Float16 f16x8 __attribute__((ext_vector_type(8)));
typedef __fp16 fp16x2 __attribute__((ext_vector_type(2)));
typedef float f32x4 __attribute__((ext_vector_type(4)));
typedef unsigned u32x4 __attribute__((ext_vector_type(4)));

#define NB 32
#define NTT 512
#define NF 1024
#define NG 4096
#define TFE (NTT * NF)
#define NWG 256
#define NTHR 512

#define W_BYTES 131072                  // [64 s][2 nt][64 lane] f16x8
#define ZQSEG 33
#define Z_FLOATS (8 * 16 * ZQSEG)
#define LDS_BYTES (W_BYTES + Z_FLOATS * 4)   // 147968
#define RINGB 65536                     // one h slot: 32 b x 1024 f16
#define RINGU (RINGB / 4)
#define SENT 0xFFFFFFFFu
#define LOG2E 1.44269504f

__device__ __forceinline__ float sigm(float v) {
  return __builtin_amdgcn_rcpf(1.0f + __builtin_amdgcn_exp2f(-LOG2E * v));
}
__device__ __forceinline__ float tanh_s(float v) {
  return 2.0f * __builtin_amdgcn_rcpf(1.0f + __builtin_amdgcn_exp2f(-2.0f * LOG2E * v)) - 1.0f;
}

__device__ __forceinline__ unsigned pk(float a, float b) {
  union { fp16x2 h2; unsigned u; } c;
  c.h2 = __builtin_amdgcn_cvt_pkrtz(a, b);
  return c.u;   // |h|<=1 -> halves never 0xFFFF
}

__device__ __forceinline__ f16x8 cvt8(f32x4 lo, f32x4 hi) {
  union { unsigned u[4]; f16x8 h8; } u;
  u.u[0] = pk(lo[0], lo[1]);
  u.u[1] = pk(lo[2], lo[3]);
  u.u[2] = pk(hi[0], hi[1]);
  u.u[3] = pk(hi[2], hi[3]);
  return u.h8;
}

// 4 coherent 16B loads; "=&v": no alias with addr %4.
__device__ __forceinline__ void ld4(f16x8 o[4], const char* p) {
  asm volatile("global_load_dwordx4 %0, %4, off sc0 sc1\n\t"
               "global_load_dwordx4 %1, %4, off offset:64 sc0 sc1\n\t"
               "global_load_dwordx4 %2, %4, off offset:128 sc0 sc1\n\t"
               "global_load_dwordx4 %3, %4, off offset:192 sc0 sc1"
               : "=&v"(o[0]), "=&v"(o[1]), "=&v"(o[2]), "=&v"(o[3])
               : "v"(p) : "memory");
}

// per-thread flag poll: wave loops until ALL its lanes see *p >= thr (vcc vote)
__device__ __forceinline__ void pollge(const unsigned* p, unsigned thr) {
  asm volatile("L%=:\n\t"
               "global_load_dword v20, %0, off sc0 sc1\n\t"
               "s_waitcnt vmcnt(0)\n\t"
               "v_cmp_lt_u32 vcc, v20, %1\n\t"
               "s_cbranch_vccnz L%="
               :: "v"(p), "v"(thr) : "memory", "v20", "vcc");
}

__device__ __forceinline__ int grp_ok(const f16x8* Tg) {
  int ok = 1;
#pragma unroll
  for (int j = 0; j < 4; ++j) {
    const u32x4 v = __builtin_bit_cast(u32x4, Tg[j]);
    ok &= (v.x != SENT) & (v.y != SENT) & (v.z != SENT) & (v.w != SENT);
  }
  return ok;
}

__global__ __launch_bounds__(NTHR, 1) void lstm_persist(
    const float* __restrict__ x,
    const float* __restrict__ Wi0, const float* __restrict__ Wh0, const float* __restrict__ bv0,
    const float* __restrict__ Wi1, const float* __restrict__ Wh1, const float* __restrict__ bv1,
    float* __restrict__ out, unsigned short* __restrict__ hring_u16,
    unsigned* __restrict__ bar) {
  extern __shared__ char lds[];
  f16x8* Wl = (f16x8*)lds;                 // Wl[(s*2+nt)*64 + lane]
  float* Zr = (float*)(lds + W_BYTES);     // Zr[(w*16+row)*33 + col]

  const int wg = blockIdx.x;
  const int tid = threadIdx.x;
  const int role = wg >> 7;        // 0: layer 0, 1: layer 1
  const int fg = wg & 127;
  const int fbase = fg * 8;
  const int w = tid >> 6;          // wave 0..7
  const int Kq = w >> 1;
  const int mt = w & 1;
  const int lane = tid & 63;
  const int lr = lane & 15;
  const int g = lane >> 4;

  const float* Wi = role ? Wi1 : Wi0;
  const float* Wh = role ? Wh1 : Wh0;
  const float* bv = role ? bv1 : bv0;
  char* h0b = (char*)hring_u16;                        // h0 ring, 8 slots
  char* h1b = (char*)hring_u16 + 8 * RINGB;            // h1 ring
  unsigned* hmu = (unsigned*)(role ? h1b : h0b);

  // sentinel-gated A-fragment phase; sbase = Kq*16 (R16 fix)
  auto hphase = [&](const char* hp, int sbase, f32x4& a0, f32x4& a1) {
    f16x8 T[16];
    ld4(T + 0, hp);       ld4(T + 4, hp + 256);
    ld4(T + 8, hp + 512); ld4(T + 12, hp + 768);
    asm volatile("s_waitcnt vmcnt(0)" ::: "memory");
    __builtin_amdgcn_sched_barrier(0);
    if (!__all(grp_ok(T) & grp_ok(T + 4) & grp_ok(T + 8) & grp_ok(T + 12))) {
      for (;;) {
        ld4(T + 0, hp);
        asm volatile("s_waitcnt vmcnt(0)" ::: "memory");
        __builtin_amdgcn_sched_barrier(0);
        if (__all(grp_ok(T))) break;
      }
      for (;;) {
        ld4(T + 4, hp + 256); ld4(T + 8, hp + 512); ld4(T + 12, hp + 768);
        asm volatile("s_waitcnt vmcnt(0)" ::: "memory");
        __builtin_amdgcn_sched_barrier(0);
        if (__all(grp_ok(T + 4) & grp_ok(T + 8) & grp_ok(T + 12))) break;
      }
    }
#pragma unroll
    for (int kk = 0; kk < 16; ++kk) {
      const int s = sbase + kk;
      a0 = __builtin_amdgcn_mfma_f32_16x16x32_f16(T[kk], Wl[(s * 2 + 0) * 64 + lane], a0, 0, 0, 0);
      a1 = __builtin_amdgcn_mfma_f32_16x16x32_f16(T[kk], Wl[(s * 2 + 1) * 64 + lane], a1, 0, 0, 0);
    }
  };

  // ---- one-time W slice -> f16 LDS in B-fragment order ----
  for (int idx = tid; idx < 16384; idx += NTHR) {
    const int k = idx >> 3, chunk = idx & 7;
    const int q = chunk >> 1, half = chunk & 1;
    const float* src = (k < NF) ? (Wi + (size_t)k * NG) : (Wh + (size_t)(k - NF) * NG);
    const f32x4 v = *(const f32x4*)(src + q * NF + fbase + half * 4);
    const int s = k >> 5, kg = (k >> 3) & 3, jj = k & 7;
#pragma unroll
    for (int j = 0; j < 4; ++j) {
      const int c = q * 8 + half * 4 + j;
      _Float16* dst = (_Float16*)&Wl[((s * 2 + (c >> 4)) * 64) + kg * 16 + (c & 15)];
      dst[jj] = (_Float16)v[j];
    }
  }
  // own ring: slot 0 = zeros, slots 1..7 = sentinel
  if (tid < 128) {
    const int b = tid >> 2, fp = tid & 3;
    unsigned* up = hmu + b * 512 + fg * 4 + fp;
    __hip_atomic_store(up, 0u, __ATOMIC_RELAXED, __HIP_MEMORY_SCOPE_AGENT);
#pragma unroll
    for (int s = 1; s < 8; ++s)
      __hip_atomic_store(up + (size_t)s * RINGU, SENT,
                         __ATOMIC_RELAXED, __HIP_MEMORY_SCOPE_AGENT);
  }
  float bias[4][2];
  if (tid < 128) {
    const int fp = tid & 3;
#pragma unroll
    for (int q = 0; q < 4; ++q) {
      bias[q][0] = bv[q * NF + fbase + 2 * fp];
      bias[q][1] = bv[q * NF + fbase + 2 * fp + 1];
    }
  }
  float cst[2] = {0.f, 0.f};

  // ---- init barrier: all WGs flag gen=1, everyone polls all 256 flags ----
  asm volatile("s_waitcnt vmcnt(0) lgkmcnt(0)\ns_barrier" ::: "memory");
  if (tid == 0)
    asm volatile("global_store_dword %0, %1, off sc0 sc1"
                 :: "v"(&bar[wg * 16]), "v"(1u) : "memory");
  if (tid < 256) pollge(&bar[tid * 16], 1u);
  __syncthreads();

  const int nrounds = role ? (NTT + 3) : NTT;   // L1 lag 3
  for (int rd = 0; rd < nrounds; ++rd) {
    const bool doit = role == 0 ? true : (rd >= 3);
    const int t = role == 0 ? rd : rd - 3;

    if (doit) {
      f32x4 a0 = {0.f, 0.f, 0.f, 0.f}, a1 = {0.f, 0.f, 0.f, 0.f};
      const int brow = mt * 16 + lr;

      if (role == 0) {
        if (Kq < 2) {
          if (w < 2 && rd >= 4)
            pollge(&bar[(128 + (tid & 127)) * 16], (unsigned)rd - 2);
          const float* xp = x + (size_t)brow * TFE + (size_t)t * NF + Kq * 512 + g * 8;
#pragma unroll
          for (int ks = 0; ks < 16; ++ks) {
            const int s = Kq * 16 + ks;
            const f32x4 al = *(const f32x4*)(xp + ks * 32);
            const f32x4 ah = *(const f32x4*)(xp + ks * 32 + 4);
            const f16x8 A = cvt8(al, ah);
            a0 = __builtin_amdgcn_mfma_f32_16x16x32_f16(A, Wl[(s * 2 + 0) * 64 + lane], a0, 0, 0, 0);
            a1 = __builtin_amdgcn_mfma_f32_16x16x32_f16(A, Wl[(s * 2 + 1) * 64 + lane], a1, 0, 0, 0);
          }
        } else {
          hphase(h0b + (size_t)(rd & 7) * RINGB + brow * 2048 + ((Kq - 2) * 512 + g * 8) * 2,
                 Kq * 16, a0, a1);    // R16 fix: was 32
        }
      } else {
        if (Kq < 2)
          hphase(h0b + (size_t)((rd - 2) & 7) * RINGB + brow * 2048 + (Kq * 512 + g * 8) * 2,
                 Kq * 16, a0, a1);    // R16 fix: was 0 (wrong for Kq=1)
        else
          hphase(h1b + (size_t)((rd - 3) & 7) * RINGB + brow * 2048 + ((Kq - 2) * 512 + g * 8) * 2,
                 Kq * 16, a0, a1);    // R16 fix: was 32
      }

      // cross-wave K reduce
      float* zb = Zr + (size_t)w * 16 * ZQSEG;
#pragma unroll
      for (int reg = 0; reg < 4; ++reg) {
        zb[(g * 4 + reg) * ZQSEG + lr] = a0[reg];
        zb[(g * 4 + reg) * ZQSEG + 16 + lr] = a1[reg];
      }
    }
    asm volatile("s_waitcnt lgkmcnt(0)\ns_barrier" ::: "memory");   // bar1

    if (doit && tid < 128) {
      const int b = tid >> 2, fp = tid & 3;
      const int bmt = b >> 4, row = b & 15;
      float hv[2];
#pragma unroll
      for (int e = 0; e < 2; ++e) {
        const int f = 2 * fp + e;
        float zq[4];
#pragma unroll
        for (int q = 0; q < 4; ++q) {
          const int c = q * 8 + f;
          float sum = bias[q][e];
#pragma unroll
          for (int kq = 0; kq < 4; ++kq)
            sum += Zr[((kq * 2 + bmt) * 16 + row) * ZQSEG + c];
          zq[q] = sum;
        }
        const float cn = sigm(zq[1]) * cst[e] + sigm(zq[0]) * tanh_s(zq[2]);
        hv[e] = sigm(zq[3]) * tanh_s(cn);
        cst[e] = cn;
      }
      // h(t+1) -> slot (t+1)&7 (write-through; consumers sentinel-detect)
      __hip_atomic_store(hmu + (size_t)((t + 1) & 7) * RINGU + b * 512 + fg * 4 + fp,
                         pk(hv[0], hv[1]), __ATOMIC_RELAXED, __HIP_MEMORY_SCOPE_AGENT);
      if (role == 1) {
        *(float2*)(out + (size_t)b * TFE + (size_t)t * NF + fbase + 2 * fp) =
            make_float2(hv[0], hv[1]);
        // re-poison consumed slots (gated: all L1 peers finished round rd-1)
        pollge(&bar[(128 + tid) * 16], (unsigned)rd + 1);
        __hip_atomic_store((unsigned*)h0b + (size_t)((rd - 3) & 7) * RINGU + b * 512 + fg * 4 + fp,
                           SENT, __ATOMIC_RELAXED, __HIP_MEMORY_SCOPE_AGENT);
        if (rd >= 4)
          __hip_atomic_store((unsigned*)h1b + (size_t)((rd - 4) & 7) * RINGU + b * 512 + fg * 4 + fp,
                             SENT, __ATOMIC_RELAXED, __HIP_MEMORY_SCOPE_AGENT);
      }
    }

    if (role == 1) {
      // full drain (h1/out/poison landed) + barrier, then progress flag
      asm volatile("s_waitcnt vmcnt(0) lgkmcnt(0)\ns_barrier" ::: "memory");
      if (tid == 0)
        asm volatile("global_store_dword %0, %1, off sc0 sc1"
                     :: "v"(&bar[wg * 16]), "v"((unsigned)(rd + 2)) : "memory");
    } else {
      asm volatile("s_waitcnt lgkmcnt(0)\ns_barrier" ::: "memory");  // bar2
    }
  }
}

extern "C" void kernel_launch(void* const* d_in, const int* in_sizes, int n_in,
                              void* d_out, int out_size, void* d_ws, size_t ws_size,
                              hipStream_t stream) {
  (void)in_sizes; (void)n_in; (void)out_size; (void)ws_size;
  const float* x   = (const float*)d_in[0];
  const float* Wi0 = (const float*)d_in[1];
  const float* Wh0 = (const float*)d_in[2];
  const float* b0  = (const float*)d_in[3];
  const float* Wi1 = (const float*)d_in[4];
  const float* Wh1 = (const float*)d_in[5];
  const float* b1  = (const float*)d_in[6];
  float* out = (float*)d_out;

  unsigned short* hring = (unsigned short*)d_ws;       // h0[8]+h1[8] slots, 1MB
  unsigned* bar = (unsigned*)((char*)d_ws + 16 * RINGB);  // 256 flags x 64B

  (void)hipMemsetAsync(bar, 0, 16384, stream);  // replay-safe flag reset

  (void)hipFuncSetAttribute((const void*)lstm_persist,
                            hipFuncAttributeMaxDynamicSharedMemorySize, LDS_BYTES);

  lstm_persist<<<dim3(NWG), dim3(NTHR), LDS_BYTES, stream>>>(
      x, Wi0, Wh0, b0, Wi1, Wh1, b1, out, hring, bar);
}